// Round 10
// baseline (169.790 us; speedup 1.0000x reference)
//
#include <hip/hip_runtime.h>
#include <stdint.h>

typedef short bf16x8 __attribute__((ext_vector_type(8)));
typedef float f32x4 __attribute__((ext_vector_type(4)));

#define NROWS 16384
#define NSLOTS 16448   // NROWS + 64 gap; = 514 * 32
#define K1DIM 256
#define MARGIN2 2e-3f

#define GLD16(g, l) __builtin_amdgcn_global_load_lds( \
    (const __attribute__((address_space(1))) uint32_t*)(g), \
    (__attribute__((address_space(3))) uint32_t*)(l), 16, 0, 0)

__device__ __forceinline__ ushort f2bf(float x) {
  union { float f; uint32_t u; } c; c.f = x;
  uint32_t u = c.u;
  return (ushort)((u + 0x7FFFu + ((u >> 16) & 1u)) >> 16);
}
__device__ __forceinline__ float bf2f(ushort h) {
  union { float f; uint32_t u; } c; c.u = ((uint32_t)h) << 16;
  return c.f;
}

// ---------------- K0: convert + hi/lo splits + all buffer inits ------------
__global__ __launch_bounds__(256) void k0_convert(
    const float* __restrict__ bd, const float* __restrict__ Wl1,
    const float* __restrict__ Wl2, const float* __restrict__ Wb1,
    ushort* __restrict__ x2bf, ushort* __restrict__ wl1t,
    ushort* __restrict__ w2t, ushort* __restrict__ wb1t,
    ushort* __restrict__ wb1lo, ushort* __restrict__ x1lo,
    int* __restrict__ rowmap, int* __restrict__ counters,
    float* __restrict__ out) {
  int i = blockIdx.x * 256 + threadIdx.x;  // grid 4096 -> 1,048,576 threads
  {
    float4 v = ((const float4*)bd)[i];
    ushort4 o;
    o.x = f2bf(v.x); o.y = f2bf(v.y); o.z = f2bf(v.z); o.w = f2bf(v.w);
    ((ushort4*)x2bf)[i] = o;
  }
  if (i < 524288) {  // x1lo: lo-residual of main-cam cols (first 128 of 256)
    int r = i >> 5, c = i & 31;
    float4 v = ((const float4*)bd)[(r << 6) + c];
    ushort4 h, l;
    h.x = f2bf(v.x); h.y = f2bf(v.y); h.z = f2bf(v.z); h.w = f2bf(v.w);
    l.x = f2bf(v.x - bf2f(h.x)); l.y = f2bf(v.y - bf2f(h.y));
    l.z = f2bf(v.z - bf2f(h.z)); l.w = f2bf(v.w - bf2f(h.w));
    ((ushort4*)x1lo)[i] = l;
  }
  if (i < 2048 * 256) {  // wl1t[n][k] = Wl1[k][n]
    int n = i >> 8, k = i & 255;
    wl1t[i] = f2bf(Wl1[k * 2048 + n]);
  }
  if (i < 96 * 2048) {   // w2t[j][k] = Wl2[k][colmap(j)]
    int j = i >> 11, k = i & 2047;
    int col = (j < 48) ? j : (1440 + j);
    w2t[i] = f2bf(Wl2[k * 1536 + col]);
  }
  if (i < 512 * 128) {   // wb1t/wb1lo [j][m] = hi/lo of Wb1[m][j]
    int j = i >> 7, m = i & 127;
    float w = Wb1[m * 512 + j];
    ushort h = f2bf(w);
    wb1t[i] = h;
    wb1lo[i] = f2bf(w - bf2f(h));
  }
  if (i < 196608) ((float4*)out)[i] = make_float4(0.f, 0.f, 0.f, 0.f);
  if (i < NSLOTS) rowmap[i] = -1;
  if (i < 8) counters[i] = 0;
}

// ---------------- K1: FUSED router (score + recheck + rowmap) --------------
__global__ __launch_bounds__(256) void k1_router(
    const ushort* __restrict__ x2bf, const ushort* __restrict__ x1lo,
    const ushort* __restrict__ wb1t, const ushort* __restrict__ wb1lo,
    const float* __restrict__ bd, const float* __restrict__ Wb1,
    const float* __restrict__ Wb2, const float* __restrict__ bb1,
    const float* __restrict__ bb2, int* __restrict__ rowmap,
    int* __restrict__ counters) {
  __shared__ __align__(1024) ushort Xh[64 * 128];   // 16 KB
  __shared__ __align__(1024) ushort Xl[64 * 128];   // 16 KB
  __shared__ __align__(1024) ushort Wh[128 * 128];  // 32 KB
  __shared__ __align__(1024) ushort Wl[128 * 128];  // 32 KB
  __shared__ float red[256];
  __shared__ float scores[64];
  __shared__ float redw[4];
  __shared__ int mlist[64];
  __shared__ int nmarg;
  const int t = threadIdx.x, ln = t & 63, wv = t >> 6;
  const int m0 = blockIdx.x << 6;
  const int q = ln >> 4, rr = ln & 15;

  if (t == 0) nmarg = 0;

#pragma unroll
  for (int ii = 0; ii < 4; ii++) {
    int inst = (wv << 2) + ii;
    int r = (inst << 2) + q;
    int sl = (rr ^ (r & 15)) << 3;
    GLD16(x2bf + (size_t)(m0 + r) * 256 + sl, Xh + (inst << 9));
    GLD16(x1lo + (size_t)(m0 + r) * 128 + sl, Xl + (inst << 9));
  }

  float s4[4][4];
#pragma unroll
  for (int a = 0; a < 4; a++)
#pragma unroll
    for (int b = 0; b < 4; b++) s4[a][b] = 0.f;

  for (int nc = 0; nc < 4; nc++) {
#pragma unroll
    for (int ii = 0; ii < 8; ii++) {
      int inst = (wv << 3) + ii;
      int jr = (inst << 2) + q;
      int jg = (nc << 7) + jr;
      int sl = (rr ^ (jr & 15)) << 3;
      GLD16(wb1t + (size_t)jg * 128 + sl, Wh + (inst << 9));
      GLD16(wb1lo + (size_t)jg * 128 + sl, Wl + (inst << 9));
    }
    __syncthreads();

    f32x4 acc[4][2] = {};
#pragma unroll
    for (int kk = 0; kk < 4; kk++) {
      int c = (kk << 2) + q;
      bf16x8 xh[4], xl[4], wh[2], wlv[2];
#pragma unroll
      for (int mi = 0; mi < 4; mi++) {
        int row = (mi << 4) + rr;
        int sl = (c ^ rr) << 3;
        xh[mi] = *(const bf16x8*)(Xh + (row << 7) + sl);
        xl[mi] = *(const bf16x8*)(Xl + (row << 7) + sl);
      }
#pragma unroll
      for (int ni = 0; ni < 2; ni++) {
        int row = (wv << 5) + (ni << 4) + rr;
        int sl = (c ^ rr) << 3;
        wh[ni] = *(const bf16x8*)(Wh + (row << 7) + sl);
        wlv[ni] = *(const bf16x8*)(Wl + (row << 7) + sl);
      }
#pragma unroll
      for (int mi = 0; mi < 4; mi++)
#pragma unroll
        for (int ni = 0; ni < 2; ni++) {
          acc[mi][ni] = __builtin_amdgcn_mfma_f32_16x16x32_bf16(
              xh[mi], wh[ni], acc[mi][ni], 0, 0, 0);
          acc[mi][ni] = __builtin_amdgcn_mfma_f32_16x16x32_bf16(
              xh[mi], wlv[ni], acc[mi][ni], 0, 0, 0);
          acc[mi][ni] = __builtin_amdgcn_mfma_f32_16x16x32_bf16(
              xl[mi], wh[ni], acc[mi][ni], 0, 0, 0);
        }
    }
    __syncthreads();

#pragma unroll
    for (int ni = 0; ni < 2; ni++) {
      int j = (nc << 7) + (wv << 5) + (ni << 4) + rr;
      float bias = bb1[j];
      float wd = Wb2[j * 2 + 1] - Wb2[j * 2];
#pragma unroll
      for (int mi = 0; mi < 4; mi++) {
        f32x4 a = acc[mi][ni];
#pragma unroll
        for (int v = 0; v < 4; v++)
          s4[mi][v] += fmaxf(a[v] + bias, 0.f) * wd;
      }
    }
  }

#pragma unroll
  for (int off = 1; off <= 8; off <<= 1)
#pragma unroll
    for (int mi = 0; mi < 4; mi++)
#pragma unroll
      for (int v = 0; v < 4; v++)
        s4[mi][v] += __shfl_xor(s4[mi][v], off);
  if (rr == 0) {
#pragma unroll
    for (int mi = 0; mi < 4; mi++)
#pragma unroll
      for (int v = 0; v < 4; v++)
        red[(wv << 6) + (mi << 4) + (q << 2) + v] = s4[mi][v];
  }
  __syncthreads();

  const float cdiff = bb2[1] - bb2[0];
  if (t < 64) {
    float s = red[t] + red[64 + t] + red[128 + t] + red[192 + t] + cdiff;
    scores[t] = s;
    if (fabsf(s) < MARGIN2) {
      int idx = atomicAdd(&nmarg, 1);
      mlist[idx] = t;
    }
  }
  __syncthreads();

  int nm = nmarg;
  for (int i = 0; i < nm; i++) {
    int row = mlist[i];
    float a0 = 0.f, a1 = 0.f;
    int j0 = t << 1;
    const float* xr = bd + (size_t)(m0 + row) * 256;
    for (int m = 0; m < 128; m++) {
      float x = xr[m];
      a0 = fmaf(x, Wb1[m * 512 + j0], a0);
      a1 = fmaf(x, Wb1[m * 512 + j0 + 1], a1);
    }
    float s = fmaxf(a0 + bb1[j0], 0.f) * (Wb2[j0 * 2 + 1] - Wb2[j0 * 2]) +
              fmaxf(a1 + bb1[j0 + 1], 0.f) * (Wb2[j0 * 2 + 3] - Wb2[j0 * 2 + 2]);
#pragma unroll
    for (int off = 1; off <= 32; off <<= 1) s += __shfl_xor(s, off);
    if (ln == 0) redw[wv] = s;
    __syncthreads();
    if (t == 0) scores[row] = redw[0] + redw[1] + redw[2] + redw[3] + cdiff;
    __syncthreads();
  }

  if (t < 64) {
    int sel = (scores[t] >= 0.f) ? 1 : 0;
    int slot = sel ? (NSLOTS - 1 - atomicAdd(&counters[2], 1))
                   : atomicAdd(&counters[1], 1);
    rowmap[slot] = m0 + t;
  }
}

// ---------------- K2: FUSED GEMM1+GEMM2, 32-row blocks, 3 blocks/CU --------
// grid (2, 514) = 1028 blocks. LDS 48 KB: Wt[256][64] 32K (Hs[32][256] 16K
// aliased) + As[32][64] 4K + Ws[48][128] 12K. G1: wave = 64 H-cols x 32 rows
// (acc 4x2). G2: wave = (rowgroup rg, k-half kq); 4 atomics/out element.
__global__ __launch_bounds__(256, 3) void k2_fused(
    const ushort* __restrict__ x2bf, const ushort* __restrict__ wl1t,
    const ushort* __restrict__ w2t, const float* __restrict__ bl1,
    const float* __restrict__ bl2, const int* __restrict__ rowmap,
    const int* __restrict__ counters, float* __restrict__ out) {
  __shared__ __align__(1024) ushort WtHs[16384];  // Wt 32K <-> Hs 16K
  __shared__ __align__(1024) ushort As[2048];     // 32 x 64, 4K
  __shared__ __align__(1024) ushort Ws[6144];     // 48 x 128, 12K
  ushort* Wt = WtHs;
  ushort* Hs = WtHs;
  const int t = threadIdx.x, ln = t & 63, wv = t >> 6;
  const int ks2 = blockIdx.x;       // n-half 0,1
  const int m0 = blockIdx.y << 5;   // 32 slot-base
  const int q = ln >> 4, rr = ln & 15;
  const int r8 = ln >> 3, s8 = ln & 7;
  const int r4 = ln >> 4, s16 = ln & 15;
  const int c0 = counters[1];
  const int sel_blk = (m0 >= c0) ? 1 : 0;
  const int selbase = sel_blk * 48;
  const int rg = wv & 1, kq = wv >> 1;   // G2 roles

  // gather index for As staging (1 inst/wave, 8 rows each)
  int g_as;
  {
    int g = rowmap[m0 + (wv << 3) + r8];
    g_as = (g < 0) ? 0 : g;
  }

  f32x4 accP[3] = {};

  for (int nc = 0; nc < 4; nc++) {
    const int n0 = (ks2 << 10) + (nc << 8);

    // ---- G1: Ht[256 H-cols x 32 rows] over K=256, 4 k64-steps ----
    f32x4 acc1[4][2] = {};
#pragma unroll 1
    for (int ks = 0; ks < 4; ks++) {
      const int kg = ks << 6;
      GLD16(x2bf + (size_t)g_as * 256 + kg + ((s8 ^ r8) << 3), As + (wv << 9));
#pragma unroll
      for (int ii = 0; ii < 8; ii++) {
        int inst = (wv << 3) + ii;
        int r = (inst << 3) + r8;
        GLD16(wl1t + (size_t)(n0 + r) * 256 + kg + ((s8 ^ r8) << 3),
              Wt + (inst << 9));
      }
      __syncthreads();
#pragma unroll
      for (int kk = 0; kk < 2; kk++) {
        int c = (kk << 2) + q;
        int sl = (c ^ (rr & 7)) << 3;
        bf16x8 af[4], bfv[2];
#pragma unroll
        for (int mi = 0; mi < 4; mi++)
          af[mi] = *(const bf16x8*)(Wt + (((wv << 6) + (mi << 4) + rr) << 6) + sl);
#pragma unroll
        for (int ni = 0; ni < 2; ni++)
          bfv[ni] = *(const bf16x8*)(As + (((ni << 4) + rr) << 6) + sl);
#pragma unroll
        for (int mi = 0; mi < 4; mi++)
#pragma unroll
          for (int ni = 0; ni < 2; ni++)
            acc1[mi][ni] = __builtin_amdgcn_mfma_f32_16x16x32_bf16(
                af[mi], bfv[ni], acc1[mi][ni], 0, 0, 0);
      }
      __syncthreads();
    }

    // ---- Hs write: lane holds 4 consecutive H-cols of one x2-row ----
#pragma unroll
    for (int mi = 0; mi < 4; mi++) {
      int p = (wv << 4) + (mi << 2) + q;  // 4-col pack 0..63
      float bias0 = bl1[n0 + (p << 2) + 0];
      float bias1 = bl1[n0 + (p << 2) + 1];
      float bias2 = bl1[n0 + (p << 2) + 2];
      float bias3 = bl1[n0 + (p << 2) + 3];
#pragma unroll
      for (int ni = 0; ni < 2; ni++) {
        int hsrow = (ni << 4) + rr;
        f32x4 a = acc1[mi][ni];
        ushort4 pk;
        pk.x = f2bf(fmaxf(a[0] + bias0, 0.f));
        pk.y = f2bf(fmaxf(a[1] + bias1, 0.f));
        pk.z = f2bf(fmaxf(a[2] + bias2, 0.f));
        pk.w = f2bf(fmaxf(a[3] + bias3, 0.f));
        *(ushort4*)(Hs + (hsrow << 8) + ((p ^ rr) << 2)) = pk;
      }
    }

    // ---- G2 in two 128-col halves; wave (rg,kq) does 16 rows x K=64 ----
#pragma unroll 1
    for (int h = 0; h < 2; h++) {
#pragma unroll
      for (int jj = 0; jj < 3; jj++) {
        int inst = wv * 3 + jj;            // 0..11, 4 rows each
        int r = (inst << 2) + r4;
        int c = s16 ^ (r & 15);
        GLD16(w2t + (size_t)(selbase + r) * 2048 + n0 + (h << 7) + (c << 3),
              Ws + (inst << 9));
      }
      __syncthreads();
#pragma unroll
      for (int kk = 0; kk < 2; kk++) {
        int p0 = (h << 5) + (kq << 4) + (kk << 3) + (q << 1);  // 4-col packs
        int hsrow = (rg << 4) + rr;
        union { ushort4 u[2]; bf16x8 v; } hu;
        hu.u[0] = *(const ushort4*)(Hs + (hsrow << 8) + ((p0 ^ rr) << 2));
        hu.u[1] = *(const ushort4*)(Hs + (hsrow << 8) + (((p0 + 1) ^ rr) << 2));
        int c2 = (kq << 3) + (kk << 2) + q;  // 8-col chunk within half
#pragma unroll
        for (int ni = 0; ni < 3; ni++) {
          int j = (ni << 4) + rr;
          bf16x8 wb = *(const bf16x8*)(Ws + (j << 7) + ((c2 ^ rr) << 3));
          accP[ni] = __builtin_amdgcn_mfma_f32_16x16x32_bf16(
              hu.v, wb, accP[ni], 0, 0, 0);
        }
      }
      __syncthreads();
    }
  }

  // ---- epilogue: wave (rg,kq) owns rows m0+rg*16+q*4+v, K-partial kq ----
  {
    float b[3] = {0.f, 0.f, 0.f};
    if (ks2 == 0 && kq == 0) {
#pragma unroll
      for (int ni = 0; ni < 3; ni++)
        b[ni] = bl2[sel_blk * 1488 + (ni << 4) + rr];
    }
#pragma unroll
    for (int v = 0; v < 4; v++) {
      int slot = m0 + (rg << 4) + (q << 2) + v;
      int orig = rowmap[slot];
      if (orig >= 0) {
        float* ob = out + (size_t)orig * 48 + rr;
        atomicAdd(ob, accP[0][v] + b[0]);
        atomicAdd(ob + 16, accP[1][v] + b[1]);
        atomicAdd(ob + 32, accP[2][v] + b[2]);
      }
    }
  }
}

extern "C" void kernel_launch(void* const* d_in, const int* in_sizes, int n_in,
                              void* d_out, int out_size, void* d_ws, size_t ws_size,
                              hipStream_t stream) {
  const float* bd  = (const float*)d_in[0];
  const float* Wl1 = (const float*)d_in[1];
  const float* bl1 = (const float*)d_in[2];
  const float* Wl2 = (const float*)d_in[3];
  const float* bl2 = (const float*)d_in[4];
  const float* Wb1 = (const float*)d_in[5];
  const float* bb1 = (const float*)d_in[6];
  const float* Wb2 = (const float*)d_in[7];
  const float* bb2 = (const float*)d_in[8];

  char* ws = (char*)d_ws;
  ushort* x2bf  = (ushort*)(ws);                  // 16384*256*2 = 8,388,608
  ushort* wl1t  = (ushort*)(ws + 8388608);        // 2048*256*2  = 1,048,576
  ushort* w2t   = (ushort*)(ws + 9437184);        // 96*2048*2   =   393,216
  ushort* x1lo  = (ushort*)(ws + 9830400);        // 16384*128*2 = 4,194,304
  ushort* wb1t  = (ushort*)(ws + 14024704);       // 512*128*2   =   131,072
  ushort* wb1lo = (ushort*)(ws + 14155776);       // 512*128*2   =   131,072
  int*    rowmap= (int*)(ws + 14286848);          // 16448*4     =    65,792
  int*    counters=(int*)(ws + 14352640);         // 8*4
  float*  outp  = (float*)d_out;

  k0_convert<<<dim3(4096), dim3(256), 0, stream>>>(
      bd, Wl1, Wl2, Wb1, x2bf, wl1t, w2t, wb1t, wb1lo, x1lo,
      rowmap, counters, outp);
  k1_router<<<dim3(256), dim3(256), 0, stream>>>(
      x2bf, x1lo, wb1t, wb1lo, bd, Wb1, Wb2, bb1, bb2, rowmap, counters);
  k2_fused<<<dim3(2, 514), dim3(256), 0, stream>>>(
      x2bf, wl1t, w2t, bl1, bl2, rowmap, counters, outp);
}

// Round 11
// 155.180 us; speedup vs baseline: 1.0941x; 1.0941x over previous
//
#include <hip/hip_runtime.h>
#include <stdint.h>

typedef short bf16x8 __attribute__((ext_vector_type(8)));
typedef float f32x4 __attribute__((ext_vector_type(4)));

#define NROWS 16384
#define NSLOTS 16448   // NROWS + 64 gap
#define K1DIM 256
#define MARGIN2 2e-3f

#define GLD16(g, l) __builtin_amdgcn_global_load_lds( \
    (const __attribute__((address_space(1))) uint32_t*)(g), \
    (__attribute__((address_space(3))) uint32_t*)(l), 16, 0, 0)

__device__ __forceinline__ ushort f2bf(float x) {
  union { float f; uint32_t u; } c; c.f = x;
  uint32_t u = c.u;
  return (ushort)((u + 0x7FFFu + ((u >> 16) & 1u)) >> 16);
}
__device__ __forceinline__ float bf2f(ushort h) {
  union { float f; uint32_t u; } c; c.u = ((uint32_t)h) << 16;
  return c.f;
}

// ---------------- K0: convert + hi/lo splits + all buffer inits ------------
__global__ __launch_bounds__(256) void k0_convert(
    const float* __restrict__ bd, const float* __restrict__ Wl1,
    const float* __restrict__ Wl2, const float* __restrict__ Wb1,
    ushort* __restrict__ x2bf, ushort* __restrict__ wl1t,
    ushort* __restrict__ w2t, ushort* __restrict__ wb1t,
    ushort* __restrict__ wb1lo, ushort* __restrict__ x1lo,
    int* __restrict__ rowmap, int* __restrict__ counters,
    float* __restrict__ out) {
  int i = blockIdx.x * 256 + threadIdx.x;  // grid 4096 -> 1,048,576 threads
  {
    float4 v = ((const float4*)bd)[i];
    ushort4 o;
    o.x = f2bf(v.x); o.y = f2bf(v.y); o.z = f2bf(v.z); o.w = f2bf(v.w);
    ((ushort4*)x2bf)[i] = o;
  }
  if (i < 524288) {  // x1lo: lo-residual of main-cam cols (first 128 of 256)
    int r = i >> 5, c = i & 31;
    float4 v = ((const float4*)bd)[(r << 6) + c];
    ushort4 h, l;
    h.x = f2bf(v.x); h.y = f2bf(v.y); h.z = f2bf(v.z); h.w = f2bf(v.w);
    l.x = f2bf(v.x - bf2f(h.x)); l.y = f2bf(v.y - bf2f(h.y));
    l.z = f2bf(v.z - bf2f(h.z)); l.w = f2bf(v.w - bf2f(h.w));
    ((ushort4*)x1lo)[i] = l;
  }
  if (i < 2048 * 256) {  // wl1t[n][k] = Wl1[k][n]
    int n = i >> 8, k = i & 255;
    wl1t[i] = f2bf(Wl1[k * 2048 + n]);
  }
  if (i < 96 * 2048) {   // w2t[j][k] = Wl2[k][colmap(j)]
    int j = i >> 11, k = i & 2047;
    int col = (j < 48) ? j : (1440 + j);
    w2t[i] = f2bf(Wl2[k * 1536 + col]);
  }
  if (i < 512 * 128) {   // wb1t/wb1lo [j][m] = hi/lo of Wb1[m][j]
    int j = i >> 7, m = i & 127;
    float w = Wb1[m * 512 + j];
    ushort h = f2bf(w);
    wb1t[i] = h;
    wb1lo[i] = f2bf(w - bf2f(h));
  }
  if (i < 196608) ((float4*)out)[i] = make_float4(0.f, 0.f, 0.f, 0.f);
  if (i < NSLOTS) rowmap[i] = -1;
  if (i < 8) counters[i] = 0;
}

// ---------------- K1: FUSED router (score + recheck + rowmap) --------------
__global__ __launch_bounds__(256) void k1_router(
    const ushort* __restrict__ x2bf, const ushort* __restrict__ x1lo,
    const ushort* __restrict__ wb1t, const ushort* __restrict__ wb1lo,
    const float* __restrict__ bd, const float* __restrict__ Wb1,
    const float* __restrict__ Wb2, const float* __restrict__ bb1,
    const float* __restrict__ bb2, int* __restrict__ rowmap,
    int* __restrict__ counters) {
  __shared__ __align__(1024) ushort Xh[64 * 128];   // 16 KB
  __shared__ __align__(1024) ushort Xl[64 * 128];   // 16 KB
  __shared__ __align__(1024) ushort Wh[128 * 128];  // 32 KB
  __shared__ __align__(1024) ushort Wl[128 * 128];  // 32 KB
  __shared__ float red[256];
  __shared__ float scores[64];
  __shared__ float redw[4];
  __shared__ int mlist[64];
  __shared__ int nmarg;
  const int t = threadIdx.x, ln = t & 63, wv = t >> 6;
  const int m0 = blockIdx.x << 6;
  const int q = ln >> 4, rr = ln & 15;

  if (t == 0) nmarg = 0;

#pragma unroll
  for (int ii = 0; ii < 4; ii++) {
    int inst = (wv << 2) + ii;
    int r = (inst << 2) + q;
    int sl = (rr ^ (r & 15)) << 3;
    GLD16(x2bf + (size_t)(m0 + r) * 256 + sl, Xh + (inst << 9));
    GLD16(x1lo + (size_t)(m0 + r) * 128 + sl, Xl + (inst << 9));
  }

  float s4[4][4];
#pragma unroll
  for (int a = 0; a < 4; a++)
#pragma unroll
    for (int b = 0; b < 4; b++) s4[a][b] = 0.f;

  for (int nc = 0; nc < 4; nc++) {
#pragma unroll
    for (int ii = 0; ii < 8; ii++) {
      int inst = (wv << 3) + ii;
      int jr = (inst << 2) + q;
      int jg = (nc << 7) + jr;
      int sl = (rr ^ (jr & 15)) << 3;
      GLD16(wb1t + (size_t)jg * 128 + sl, Wh + (inst << 9));
      GLD16(wb1lo + (size_t)jg * 128 + sl, Wl + (inst << 9));
    }
    __syncthreads();

    f32x4 acc[4][2] = {};
#pragma unroll
    for (int kk = 0; kk < 4; kk++) {
      int c = (kk << 2) + q;
      bf16x8 xh[4], xl[4], wh[2], wlv[2];
#pragma unroll
      for (int mi = 0; mi < 4; mi++) {
        int row = (mi << 4) + rr;
        int sl = (c ^ rr) << 3;
        xh[mi] = *(const bf16x8*)(Xh + (row << 7) + sl);
        xl[mi] = *(const bf16x8*)(Xl + (row << 7) + sl);
      }
#pragma unroll
      for (int ni = 0; ni < 2; ni++) {
        int row = (wv << 5) + (ni << 4) + rr;
        int sl = (c ^ rr) << 3;
        wh[ni] = *(const bf16x8*)(Wh + (row << 7) + sl);
        wlv[ni] = *(const bf16x8*)(Wl + (row << 7) + sl);
      }
#pragma unroll
      for (int mi = 0; mi < 4; mi++)
#pragma unroll
        for (int ni = 0; ni < 2; ni++) {
          acc[mi][ni] = __builtin_amdgcn_mfma_f32_16x16x32_bf16(
              xh[mi], wh[ni], acc[mi][ni], 0, 0, 0);
          acc[mi][ni] = __builtin_amdgcn_mfma_f32_16x16x32_bf16(
              xh[mi], wlv[ni], acc[mi][ni], 0, 0, 0);
          acc[mi][ni] = __builtin_amdgcn_mfma_f32_16x16x32_bf16(
              xl[mi], wh[ni], acc[mi][ni], 0, 0, 0);
        }
    }
    __syncthreads();

#pragma unroll
    for (int ni = 0; ni < 2; ni++) {
      int j = (nc << 7) + (wv << 5) + (ni << 4) + rr;
      float bias = bb1[j];
      float wd = Wb2[j * 2 + 1] - Wb2[j * 2];
#pragma unroll
      for (int mi = 0; mi < 4; mi++) {
        f32x4 a = acc[mi][ni];
#pragma unroll
        for (int v = 0; v < 4; v++)
          s4[mi][v] += fmaxf(a[v] + bias, 0.f) * wd;
      }
    }
  }

#pragma unroll
  for (int off = 1; off <= 8; off <<= 1)
#pragma unroll
    for (int mi = 0; mi < 4; mi++)
#pragma unroll
      for (int v = 0; v < 4; v++)
        s4[mi][v] += __shfl_xor(s4[mi][v], off);
  if (rr == 0) {
#pragma unroll
    for (int mi = 0; mi < 4; mi++)
#pragma unroll
      for (int v = 0; v < 4; v++)
        red[(wv << 6) + (mi << 4) + (q << 2) + v] = s4[mi][v];
  }
  __syncthreads();

  const float cdiff = bb2[1] - bb2[0];
  if (t < 64) {
    float s = red[t] + red[64 + t] + red[128 + t] + red[192 + t] + cdiff;
    scores[t] = s;
    if (fabsf(s) < MARGIN2) {
      int idx = atomicAdd(&nmarg, 1);
      mlist[idx] = t;
    }
  }
  __syncthreads();

  int nm = nmarg;
  for (int i = 0; i < nm; i++) {
    int row = mlist[i];
    float a0 = 0.f, a1 = 0.f;
    int j0 = t << 1;
    const float* xr = bd + (size_t)(m0 + row) * 256;
    for (int m = 0; m < 128; m++) {
      float x = xr[m];
      a0 = fmaf(x, Wb1[m * 512 + j0], a0);
      a1 = fmaf(x, Wb1[m * 512 + j0 + 1], a1);
    }
    float s = fmaxf(a0 + bb1[j0], 0.f) * (Wb2[j0 * 2 + 1] - Wb2[j0 * 2]) +
              fmaxf(a1 + bb1[j0 + 1], 0.f) * (Wb2[j0 * 2 + 3] - Wb2[j0 * 2 + 2]);
#pragma unroll
    for (int off = 1; off <= 32; off <<= 1) s += __shfl_xor(s, off);
    if (ln == 0) redw[wv] = s;
    __syncthreads();
    if (t == 0) scores[row] = redw[0] + redw[1] + redw[2] + redw[3] + cdiff;
    __syncthreads();
  }

  if (t < 64) {
    int sel = (scores[t] >= 0.f) ? 1 : 0;
    int slot = sel ? (NSLOTS - 1 - atomicAdd(&counters[2], 1))
                   : atomicAdd(&counters[1], 1);
    rowmap[slot] = m0 + t;
  }
}

// ---------------- K2: FUSED GEMM1+GEMM2, 4-way col split -------------------
// grid (4, 257) = 1028 blocks (4.0/CU supply, 3/CU resident at 52 KB LDS).
// Block: 64 row-slots x 512 cols (quarter). Internals identical to the
// proven R8 structure; nc loop is 2 x 256-col chunks; atomic epilogue sums
// the 4 K-partials; bias added by ks2==0 only.
__global__ __launch_bounds__(256, 3) void k2_fused(
    const ushort* __restrict__ x2bf, const ushort* __restrict__ wl1t,
    const ushort* __restrict__ w2t, const float* __restrict__ bl1,
    const float* __restrict__ bl2, const int* __restrict__ rowmap,
    const int* __restrict__ counters, float* __restrict__ out) {
  __shared__ __align__(1024) ushort As[4096];     // x2 [64 r][64 k] / kstep
  __shared__ __align__(1024) ushort WtHs[16384];  // Wt[256][64] <-> Hs[64][256]
  __shared__ __align__(1024) ushort Ws[6144];     // W2 [48][128 half]
  ushort* Wt = WtHs;
  ushort* Hs = WtHs;
  const int t = threadIdx.x, ln = t & 63, wv = t >> 6;
  const int ks2 = blockIdx.x;       // col quarter 0..3
  const int m0 = blockIdx.y << 6;   // 64 slot-base
  const int q = ln >> 4, rr = ln & 15;
  const int r8 = ln >> 3, s8 = ln & 7;
  const int r4 = ln >> 4, s16 = ln & 15;
  const int c0 = counters[1];
  const int sel_blk = (m0 >= c0) ? 1 : 0;
  const int selbase = sel_blk * 48;

  int g_as[2];
#pragma unroll
  for (int ii = 0; ii < 2; ii++) {
    int g = rowmap[m0 + (((wv << 1) + ii) << 3) + r8];
    g_as[ii] = (g < 0) ? 0 : g;
  }

  f32x4 accP[3] = {};

  for (int nc = 0; nc < 2; nc++) {
    const int n0 = (ks2 << 9) + (nc << 8);

    f32x4 acc1[4][4] = {};
#pragma unroll 1
    for (int ks = 0; ks < 4; ks++) {
      const int kg = ks << 6;
#pragma unroll
      for (int ii = 0; ii < 2; ii++)
        GLD16(x2bf + (size_t)g_as[ii] * 256 + kg + ((s8 ^ r8) << 3),
              As + ((((wv << 1) + ii)) << 9));
#pragma unroll
      for (int ii = 0; ii < 8; ii++) {
        int inst = (wv << 3) + ii;
        int r = (inst << 3) + r8;
        GLD16(wl1t + (size_t)(n0 + r) * 256 + kg + ((s8 ^ r8) << 3),
              Wt + (inst << 9));
      }
      __syncthreads();
#pragma unroll
      for (int kk = 0; kk < 2; kk++) {
        int c = (kk << 2) + q;
        int sl = (c ^ (rr & 7)) << 3;
        bf16x8 af[4], bfv[4];
#pragma unroll
        for (int mi = 0; mi < 4; mi++)
          af[mi] = *(const bf16x8*)(Wt + (((wv << 6) + (mi << 4) + rr) << 6) + sl);
#pragma unroll
        for (int ni = 0; ni < 4; ni++)
          bfv[ni] = *(const bf16x8*)(As + (((ni << 4) + rr) << 6) + sl);
#pragma unroll
        for (int mi = 0; mi < 4; mi++)
#pragma unroll
          for (int ni = 0; ni < 4; ni++)
            acc1[mi][ni] = __builtin_amdgcn_mfma_f32_16x16x32_bf16(
                af[mi], bfv[ni], acc1[mi][ni], 0, 0, 0);
      }
      __syncthreads();
    }

#pragma unroll
    for (int mi = 0; mi < 4; mi++) {
      int p = (wv << 4) + (mi << 2) + q;
      float bias0 = bl1[n0 + (p << 2) + 0];
      float bias1 = bl1[n0 + (p << 2) + 1];
      float bias2 = bl1[n0 + (p << 2) + 2];
      float bias3 = bl1[n0 + (p << 2) + 3];
#pragma unroll
      for (int ni = 0; ni < 4; ni++) {
        int hsrow = (ni << 4) + rr;
        f32x4 a = acc1[mi][ni];
        ushort4 pk;
        pk.x = f2bf(fmaxf(a[0] + bias0, 0.f));
        pk.y = f2bf(fmaxf(a[1] + bias1, 0.f));
        pk.z = f2bf(fmaxf(a[2] + bias2, 0.f));
        pk.w = f2bf(fmaxf(a[3] + bias3, 0.f));
        *(ushort4*)(Hs + (hsrow << 8) + ((p ^ rr) << 2)) = pk;
      }
    }

#pragma unroll 1
    for (int h = 0; h < 2; h++) {
#pragma unroll
      for (int jj = 0; jj < 3; jj++) {
        int inst = wv * 3 + jj;
        int r = (inst << 2) + r4;
        int c = s16 ^ (r & 15);
        GLD16(w2t + (size_t)(selbase + r) * 2048 + n0 + (h << 7) + (c << 3),
              Ws + (inst << 9));
      }
      __syncthreads();
#pragma unroll
      for (int kk = 0; kk < 4; kk++) {
        int p0 = (h << 5) + (kk << 3) + (q << 1);
        int hrow = (wv << 4) + rr;
        union { ushort4 u[2]; bf16x8 v; } hu;
        hu.u[0] = *(const ushort4*)(Hs + (hrow << 8) + ((p0 ^ rr) << 2));
        hu.u[1] = *(const ushort4*)(Hs + (hrow << 8) + (((p0 + 1) ^ rr) << 2));
        int c = (kk << 2) + q;
#pragma unroll
        for (int ni = 0; ni < 3; ni++) {
          bf16x8 wb = *(const bf16x8*)(Ws + (((ni << 4) + rr) << 7) +
                                       ((c ^ rr) << 3));
          accP[ni] = __builtin_amdgcn_mfma_f32_16x16x32_bf16(
              hu.v, wb, accP[ni], 0, 0, 0);
        }
      }
      __syncthreads();
    }
  }

  {
    float b[3] = {0.f, 0.f, 0.f};
    if (ks2 == 0) {
#pragma unroll
      for (int ni = 0; ni < 3; ni++)
        b[ni] = bl2[sel_blk * 1488 + (ni << 4) + rr];
    }
#pragma unroll
    for (int v = 0; v < 4; v++) {
      int slot = m0 + (wv << 4) + (q << 2) + v;
      int orig = rowmap[slot];
      if (orig >= 0) {
        float* ob = out + (size_t)orig * 48 + rr;
        atomicAdd(ob, accP[0][v] + b[0]);
        atomicAdd(ob + 16, accP[1][v] + b[1]);
        atomicAdd(ob + 32, accP[2][v] + b[2]);
      }
    }
  }
}

extern "C" void kernel_launch(void* const* d_in, const int* in_sizes, int n_in,
                              void* d_out, int out_size, void* d_ws, size_t ws_size,
                              hipStream_t stream) {
  const float* bd  = (const float*)d_in[0];
  const float* Wl1 = (const float*)d_in[1];
  const float* bl1 = (const float*)d_in[2];
  const float* Wl2 = (const float*)d_in[3];
  const float* bl2 = (const float*)d_in[4];
  const float* Wb1 = (const float*)d_in[5];
  const float* bb1 = (const float*)d_in[6];
  const float* Wb2 = (const float*)d_in[7];
  const float* bb2 = (const float*)d_in[8];

  char* ws = (char*)d_ws;
  ushort* x2bf  = (ushort*)(ws);                  // 16384*256*2 = 8,388,608
  ushort* wl1t  = (ushort*)(ws + 8388608);        // 2048*256*2  = 1,048,576
  ushort* w2t   = (ushort*)(ws + 9437184);        // 96*2048*2   =   393,216
  ushort* x1lo  = (ushort*)(ws + 9830400);        // 16384*128*2 = 4,194,304
  ushort* wb1t  = (ushort*)(ws + 14024704);       // 512*128*2   =   131,072
  ushort* wb1lo = (ushort*)(ws + 14155776);       // 512*128*2   =   131,072
  int*    rowmap= (int*)(ws + 14286848);          // 16448*4     =    65,792
  int*    counters=(int*)(ws + 14352640);         // 8*4
  float*  outp  = (float*)d_out;

  k0_convert<<<dim3(4096), dim3(256), 0, stream>>>(
      bd, Wl1, Wl2, Wb1, x2bf, wl1t, w2t, wb1t, wb1lo, x1lo,
      rowmap, counters, outp);
  k1_router<<<dim3(256), dim3(256), 0, stream>>>(
      x2bf, x1lo, wb1t, wb1lo, bd, Wb1, Wb2, bb1, bb2, rowmap, counters);
  k2_fused<<<dim3(4, 257), dim3(256), 0, stream>>>(
      x2bf, wl1t, w2t, bl1, bl2, rowmap, counters, outp);
}